// Round 2
// baseline (4579.334 us; speedup 1.0000x reference)
//
#include <hip/hip_runtime.h>

// StochasticRegionalConvolution on MI355X.
// Identity: out[b,c,p,q] = coeff(p,q) * conv3x3(x)[b,c,p,q] / 16,
// where coeff(p,q) = sum_t lam_t * [p,q inside region t].
// Kernel 1 builds coeff (256x256 f32 in d_ws); kernel 2 does a masked direct conv.

#define HH 256
#define WW 256
#define CH 64
#define OUTR 62          // r - k + 1 per-region valid size
#define TILE_H 32
#define TILE_W 64

__global__ void srconv_coeff_kernel(const int* __restrict__ h_idx,
                                    const int* __restrict__ w_idx,
                                    const float* __restrict__ lam,
                                    int T, float* __restrict__ coeff) {
    int p = blockIdx.x;
    int q = threadIdx.x;
    float c = 0.f;
    for (int t = 0; t < T; ++t) {
        int dh = p - h_idx[t];
        int dw = q - w_idx[t];
        if (dh >= 0 && dh < OUTR && dw >= 0 && dw < OUTR) c += lam[t];
    }
    coeff[(p << 8) + q] = c * (1.0f / 16.0f);   // n_r = (256/64)*(256/64) = 16
}

__launch_bounds__(256, 2)
__global__ void srconv_conv_kernel(const float* __restrict__ x,
                                   const float* __restrict__ wgt,
                                   const float* __restrict__ coeff,
                                   float* __restrict__ out) {
    // x tile: 8 cin x (32+2) rows x (64+2) cols, rows padded to 68 floats so
    // every row base is 8B-aligned (float2 reads) and staging stays coalesced.
    __shared__ float xs[8][34][68];          // 73,984 B
    __shared__ float wls[4][8][9];           //  1,152 B

    const int tid = threadIdx.x;
    const int tx = tid & 31;                 // -> column pair
    const int ty = tid >> 5;                 // -> row quad
    const int s  = blockIdx.x;
    const int b  = blockIdx.y;
    const int P0 = (s >> 2) * TILE_H;
    const int Q0 = (s & 3) * TILE_W;

    const int r0 = ty * 4;                   // LDS-local first output row
    const int c0 = tx * 2;                   // LDS-local first output col

    // Preload the 8 per-pixel coefficients (reused for all 16 c_out groups)
    float cf[8];
    float cmax = 0.f;
#pragma unroll
    for (int i = 0; i < 4; ++i)
#pragma unroll
        for (int j = 0; j < 2; ++j) {
            cf[i * 2 + j] = coeff[((P0 + r0 + i) << 8) + (Q0 + c0 + j)];
            cmax = fmaxf(cmax, cf[i * 2 + j]);
        }

    // Fully-uncovered tile: write zeros, skip all compute (uniform branch)
    int any = __syncthreads_count(cmax > 0.f);
    if (any == 0) {
        for (int co = 0; co < CH; ++co) {
            int base = ((b << 6) + co) << 16;
#pragma unroll
            for (int i = 0; i < 4; ++i) {
                *reinterpret_cast<float2*>(
                    &out[base + ((P0 + r0 + i) << 8) + Q0 + c0]) =
                    make_float2(0.f, 0.f);
            }
        }
        return;
    }

    for (int cog = 0; cog < 16; ++cog) {         // c_out groups of 4
        float acc[4][8];
#pragma unroll
        for (int a = 0; a < 4; ++a)
#pragma unroll
            for (int pix = 0; pix < 8; ++pix) acc[a][pix] = 0.f;

        for (int cb = 0; cb < 8; ++cb) {         // cin chunks of 8
            __syncthreads();                     // protect LDS from prev readers
            // stage x chunk: 8 cin x 34 rows x 66 cols (coalesced along cols)
            for (int idx = tid; idx < 8 * 34 * 66; idx += 256) {
                int cin = idx / (34 * 66);
                int rem = idx - cin * (34 * 66);
                int row = rem / 66;
                int col = rem - row * 66;
                int gr = P0 + row, gc = Q0 + col;
                float v = 0.f;
                if (gr < HH && gc < WW)
                    v = x[(((b << 6) + (cb << 3) + cin) << 16) + (gr << 8) + gc];
                xs[cin][row][col] = v;
            }
            // stage weights for this (cog, cb): 4 co x 8 cin x 9 = 288 elems
            // (strided loop: 288 > blockDim, a plain `if (tid<288)` left
            //  elements 256..287 unwritten — that was the round-1 bug)
            for (int idx = tid; idx < 288; idx += 256) {
                int co  = idx / 72;
                int rem = idx - co * 72;
                int ci  = rem / 9;
                int kk  = rem - ci * 9;
                wls[co][ci][kk] =
                    wgt[(((cog * 4 + co) << 6) + (cb << 3) + ci) * 9 + kk];
            }
            __syncthreads();

            for (int cin = 0; cin < 8; ++cin) {
                // 6x4 x-window registers cover this thread's 4x2 output pixels
                float xv[6][4];
#pragma unroll
                for (int ii = 0; ii < 6; ++ii) {
                    float2 lo = *reinterpret_cast<const float2*>(
                        &xs[cin][r0 + ii][c0]);
                    float2 hi = *reinterpret_cast<const float2*>(
                        &xs[cin][r0 + ii][c0 + 2]);
                    xv[ii][0] = lo.x; xv[ii][1] = lo.y;
                    xv[ii][2] = hi.x; xv[ii][3] = hi.y;
                }
#pragma unroll
                for (int co = 0; co < 4; ++co) {
                    float wv[9];
#pragma unroll
                    for (int kk = 0; kk < 9; ++kk) wv[kk] = wls[co][cin][kk];
#pragma unroll
                    for (int i = 0; i < 4; ++i)
#pragma unroll
                        for (int kh = 0; kh < 3; ++kh)
#pragma unroll
                            for (int j = 0; j < 2; ++j)
#pragma unroll
                                for (int kw = 0; kw < 3; ++kw)
                                    acc[co][i * 2 + j] =
                                        fmaf(xv[i + kh][j + kw],
                                             wv[kh * 3 + kw],
                                             acc[co][i * 2 + j]);
                }
            }
        }

        // epilogue: scale by coeff, float2 stores (coalesced across tx)
#pragma unroll
        for (int co = 0; co < 4; ++co) {
            int base = ((b << 6) + cog * 4 + co) << 16;
#pragma unroll
            for (int i = 0; i < 4; ++i) {
                float2 v = make_float2(acc[co][i * 2 + 0] * cf[i * 2 + 0],
                                       acc[co][i * 2 + 1] * cf[i * 2 + 1]);
                *reinterpret_cast<float2*>(
                    &out[base + ((P0 + r0 + i) << 8) + Q0 + c0]) = v;
            }
        }
    }
}

extern "C" void kernel_launch(void* const* d_in, const int* in_sizes, int n_in,
                              void* d_out, int out_size, void* d_ws, size_t ws_size,
                              hipStream_t stream) {
    const float* x     = (const float*)d_in[0];
    const float* wgt   = (const float*)d_in[1];
    const int*   h_idx = (const int*)d_in[2];
    const int*   w_idx = (const int*)d_in[3];
    const float* lam   = (const float*)d_in[4];
    float*       out   = (float*)d_out;
    float*       coeff = (float*)d_ws;          // 256*256 f32 = 256 KB scratch
    const int    T     = in_sizes[2];

    srconv_coeff_kernel<<<256, 256, 0, stream>>>(h_idx, w_idx, lam, T, coeff);
    // grid: 32 spatial tiles (8 x 4 of 32x64) x 16 batches
    srconv_conv_kernel<<<dim3(32, 16), 256, 0, stream>>>(x, wgt, coeff, out);
}

// Round 3
// 295.638 us; speedup vs baseline: 15.4897x; 15.4897x over previous
//
#include <hip/hip_runtime.h>

// StochasticRegionalConvolution, MFMA version.
// out[b,co,p,q] = coeff(p,q) * sum_{ci,kh,kw} x[b,ci,p+kh,q+kw] * W[co,ci,kh,kw]
// coeff(p,q) = sum_t lam_t * [region t covers (p,q)] / 16, zero for p,q > 253.
//
// Kernel 1: coeff map (256x256 f32) -> d_ws[0 .. 256KB)
// Kernel 2: weight transform -> MFMA A-fragment order, bf16 -> d_ws[256KB ..)
//   afrag[fi][lane][j] = W[co=m*16+(lane&15)][ci=cb*32+(lane>>4)*8+j][kh][kw]
//   fi = (kk*2+cb)*4+m, kk = kh*3+kw.   (16B per lane -> coalesced dwordx4)
// Kernel 3: conv. Block = 256 thr = 4 waves, pixel tile 16x16, full 64 c_out.
//   x tile staged once to LDS bf16 [18][18][64ci] with XOR swizzle; K-loop
//   = 9 (kh,kw) x 2 ci-halves, B-frags via ds_read_b128, A-frags from global.

typedef short short8 __attribute__((ext_vector_type(8)));
typedef float floatx4 __attribute__((ext_vector_type(4)));
typedef unsigned int uint4v __attribute__((ext_vector_type(4)));

#define OUTR 62

__device__ inline unsigned f2bf_pack(float lo, float hi) {
    unsigned ul = __builtin_bit_cast(unsigned, lo);
    unsigned uh = __builtin_bit_cast(unsigned, hi);
    ul = (ul + 0x7FFFu + ((ul >> 16) & 1u)) >> 16;   // RNE
    uh = (uh + 0x7FFFu + ((uh >> 16) & 1u)) >> 16;
    return ul | (uh << 16);
}

__global__ void srconv_coeff_kernel(const int* __restrict__ h_idx,
                                    const int* __restrict__ w_idx,
                                    const float* __restrict__ lam,
                                    int T, float* __restrict__ coeff) {
    int p = blockIdx.x;
    int q = threadIdx.x;
    float c = 0.f;
    for (int t = 0; t < T; ++t) {
        int dh = p - h_idx[t];
        int dw = q - w_idx[t];
        if (dh >= 0 && dh < OUTR && dw >= 0 && dw < OUTR) c += lam[t];
    }
    coeff[(p << 8) + q] = c * (1.0f / 16.0f);
}

__global__ void srconv_wtrans_kernel(const float* __restrict__ wgt,
                                     uint4v* __restrict__ afrag) {
    int id = blockIdx.x * 256 + threadIdx.x;      // [0, 72*64)
    int l  = id & 63;
    int fi = id >> 6;                             // (kk*2+cb)*4 + m
    int m  = fi & 3;
    int cb = (fi >> 2) & 1;
    int kk = fi >> 3;
    int co  = m * 16 + (l & 15);
    int ci0 = cb * 32 + (l >> 4) * 8;
    float w[8];
#pragma unroll
    for (int j = 0; j < 8; ++j)
        w[j] = wgt[(co * 64 + ci0 + j) * 9 + kk];
    uint4v d;
    d.x = f2bf_pack(w[0], w[1]);
    d.y = f2bf_pack(w[2], w[3]);
    d.z = f2bf_pack(w[4], w[5]);
    d.w = f2bf_pack(w[6], w[7]);
    afrag[id] = d;
}

__launch_bounds__(256, 2)
__global__ void srconv_mfma_kernel(const float* __restrict__ x,
                                   const float* __restrict__ coeff,
                                   const short8* __restrict__ afrag,
                                   float* __restrict__ out) {
    __shared__ __align__(16) short xs[18 * 18 * 64];   // 41,472 B

    const int tid  = threadIdx.x;
    const int lane = tid & 63;
    const int wv   = tid >> 6;        // wave 0..3 -> pixel rows wv*4..wv*4+3
    const int l15  = lane & 15;
    const int kg   = lane >> 4;

    const int tile = blockIdx.x;      // 16x16 spatial tiles
    const int b    = blockIdx.y;
    const int P0   = (tile >> 4) << 4;
    const int Q0   = (tile & 15) << 4;

    // ---- tile skip test (1 coeff per thread, 16x16 tile) ----
    float myc = coeff[((P0 + (tid >> 4)) << 8) + Q0 + (tid & 15)];
    if (__syncthreads_count(myc != 0.f) == 0) {
        int r = tid >> 4, c = tid & 15;
        float* op = out + ((b << 6) << 16) + ((P0 + r) << 8) + Q0 + c;
        for (int co = 0; co < 64; ++co) op[co << 16] = 0.f;
        return;
    }

    // ---- stage x tile: [18 rows][18 cols][64 ci] bf16, swizzled ----
    // 8 ci per iteration -> one ds_write_b128. 8*18*18 = 2592 iterations.
    for (int idx = tid; idx < 8 * 18 * 18; idx += 256) {
        int cp8 = idx / (18 * 18);
        int rem = idx - cp8 * (18 * 18);
        int row = rem / 18;
        int col = rem - row * 18;
        int gr = min(P0 + row, 255);           // clamped edges feed coeff==0
        int gc = min(Q0 + col, 255);
        const float* xp = x + (((b << 6) + (cp8 << 3)) << 16) + (gr << 8) + gc;
        float v0 = xp[0 << 16], v1 = xp[1 << 16], v2 = xp[2 << 16], v3 = xp[3 << 16];
        float v4 = xp[4 << 16], v5 = xp[5 << 16], v6 = xp[6 << 16], v7 = xp[7 << 16];
        uint4v d;
        d.x = f2bf_pack(v0, v1);
        d.y = f2bf_pack(v2, v3);
        d.z = f2bf_pack(v4, v5);
        d.w = f2bf_pack(v6, v7);
        int off = ((row * 18 + col) << 6) + (cp8 << 3);   // element (short) offset
        off ^= (col & 7) << 3;                            // T2 swizzle
        *(uint4v*)(&xs[off]) = d;
    }
    __syncthreads();

    // ---- K-loop: 9 taps x 2 ci-halves, 16 MFMA each ----
    floatx4 acc[4][4];
#pragma unroll
    for (int m = 0; m < 4; ++m)
#pragma unroll
        for (int n = 0; n < 4; ++n) acc[m][n] = (floatx4){0.f, 0.f, 0.f, 0.f};

    const int w4 = wv << 2;
#pragma unroll
    for (int kk = 0; kk < 9; ++kk) {
        const int kh = kk / 3;
        const int kw = kk - kh * 3;
        const int col = kw + l15;                         // LDS col for B
        const int cswz = (col & 7) << 3;
#pragma unroll
        for (int cb = 0; cb < 2; ++cb) {
            short8 a[4];
#pragma unroll
            for (int m = 0; m < 4; ++m)
                a[m] = afrag[((((kk << 1) + cb) << 2) + m) * 64 + lane];
            short8 bf[4];
#pragma unroll
            for (int n = 0; n < 4; ++n) {
                int lrow = w4 + n + kh;
                int off = (((lrow * 18 + col) << 6) + (cb << 5) + (kg << 3)) ^ cswz;
                bf[n] = *(const short8*)(&xs[off]);
            }
#pragma unroll
            for (int m = 0; m < 4; ++m)
#pragma unroll
                for (int n = 0; n < 4; ++n)
                    acc[m][n] = __builtin_amdgcn_mfma_f32_16x16x32_bf16(
                        a[m], bf[n], acc[m][n], 0, 0, 0);
        }
    }

    // ---- epilogue: scale by coeff, store f32 ----
    // D layout (verified m89): col = lane&15 -> q, row = (lane>>4)*4+reg -> co
#pragma unroll
    for (int n = 0; n < 4; ++n) {
        int pr = P0 + w4 + n;
        float cf = coeff[(pr << 8) + Q0 + l15];
#pragma unroll
        for (int m = 0; m < 4; ++m) {
#pragma unroll
            for (int reg = 0; reg < 4; ++reg) {
                int co = (m << 4) + (kg << 2) + reg;
                out[(((b << 6) + co) << 16) + (pr << 8) + Q0 + l15] =
                    acc[m][n][reg] * cf;
            }
        }
    }
}

extern "C" void kernel_launch(void* const* d_in, const int* in_sizes, int n_in,
                              void* d_out, int out_size, void* d_ws, size_t ws_size,
                              hipStream_t stream) {
    const float* x     = (const float*)d_in[0];
    const float* wgt   = (const float*)d_in[1];
    const int*   h_idx = (const int*)d_in[2];
    const int*   w_idx = (const int*)d_in[3];
    const float* lam   = (const float*)d_in[4];
    float*       out   = (float*)d_out;
    float*       coeff = (float*)d_ws;                       // 256 KB
    char*        af_b  = (char*)d_ws + 65536 * sizeof(float);
    const int    T     = in_sizes[2];

    srconv_coeff_kernel<<<256, 256, 0, stream>>>(h_idx, w_idx, lam, T, coeff);
    srconv_wtrans_kernel<<<18, 256, 0, stream>>>(wgt, (uint4v*)af_b);
    srconv_mfma_kernel<<<dim3(256, 16), 256, 0, stream>>>(
        x, coeff, (const short8*)af_b, out);
}